// Round 2
// baseline (52143.958 us; speedup 1.0000x reference)
//
#include <hip/hip_runtime.h>
#include <stdint.h>

// GRU  B=128, T=1024, IN=256, H=512, OUT=1  (all fp32)
//
// v2: 256 wgs x 512 thr persistent kernel (8 waves/CU, 2/SIMD for TLP).
//   8 groups x 32 wgs; group owns 16 samples, wg owns 16 hidden j.
//   Thread (j_loc in [0,16), ks in [0,32)) holds W_hh[3][j][16ks..+16) (48 f)
//   and W_ih[3][j][8ks..+8) (24 f) in REGISTERS -> no spills at <=256 VGPR.
//   x staged through LDS double buffer (loads issued at step top, ds_write
//   after compute = latency hidden); XOR-swizzled (blk^=(blk>>3)&3) so
//   stride-32B b128 reads are 2-way (free) instead of 8-way conflicted.
//   h exchanged via global double buffer + per-group monotonic atomic barrier.

#define B_   128
#define T_   1024
#define IN_  256
#define H_   512
#define NG   8
#define WPG  32
#define SG   16
#define JT   16
#define NT   512

__device__ __forceinline__ float sig_(float v){ return 1.0f/(1.0f + __expf(-v)); }
__device__ __forceinline__ float tanh_(float v){
  float e = __expf(2.0f*v);            // tanh = 1 - 2/(e^{2x}+1); inf-safe
  return 1.0f - 2.0f/(e + 1.0f);
}

#define FMA4(acc, v, warr, base) do{            \
  acc = fmaf((v).x, warr[(base)+0], acc);       \
  acc = fmaf((v).y, warr[(base)+1], acc);       \
  acc = fmaf((v).z, warr[(base)+2], acc);       \
  acc = fmaf((v).w, warr[(base)+3], acc); }while(0)

__device__ __forceinline__ int swz_(int blk){ return blk ^ ((blk>>3)&3); }  // involution

__global__ void __launch_bounds__(NT, 2)
rnn_persist(const float* __restrict__ x, const float* __restrict__ W_ih,
            const float* __restrict__ W_hh, const float* __restrict__ bias,
            const float* __restrict__ bias_n, float* __restrict__ h_buf,
            int* __restrict__ counters)
{
  const int bid   = (int)blockIdx.x;
  const int g     = bid & (NG-1);
  const int w     = bid >> 3;
  const int tid   = (int)threadIdx.x;
  const int j_loc = tid >> 5;          // [0,16)
  const int ks    = tid & 31;          // [0,32)
  const int jg    = w*JT + j_loc;
  const int b0    = g*SG;
  const int kh    = ks*16;             // W_hh k-chunk start
  const int kx    = ks*8;              // W_ih k-chunk start

  __shared__ float hnew_sh[SG][JT];
  __shared__ float xbuf[2][SG*IN_];    // 32 KB double-buffered x tile

  // ---- weights into registers ----
  float wr[16], wz[16], wn[16];
#pragma unroll
  for (int i=0;i<4;i++){
    const float4 a  = *(const float4*)&W_hh[(size_t)(      jg)*H_ + kh + 4*i];
    const float4 b4 = *(const float4*)&W_hh[(size_t)(H_  + jg)*H_ + kh + 4*i];
    const float4 c  = *(const float4*)&W_hh[(size_t)(2*H_+ jg)*H_ + kh + 4*i];
    wr[4*i+0]=a.x;  wr[4*i+1]=a.y;  wr[4*i+2]=a.z;  wr[4*i+3]=a.w;
    wz[4*i+0]=b4.x; wz[4*i+1]=b4.y; wz[4*i+2]=b4.z; wz[4*i+3]=b4.w;
    wn[4*i+0]=c.x;  wn[4*i+1]=c.y;  wn[4*i+2]=c.z;  wn[4*i+3]=c.w;
  }
  float wxr[8], wxz[8], wxn[8];
#pragma unroll
  for (int i=0;i<2;i++){
    const float4 a  = *(const float4*)&W_ih[(size_t)(      jg)*IN_ + kx + 4*i];
    const float4 b4 = *(const float4*)&W_ih[(size_t)(H_  + jg)*IN_ + kx + 4*i];
    const float4 c  = *(const float4*)&W_ih[(size_t)(2*H_+ jg)*IN_ + kx + 4*i];
    wxr[4*i+0]=a.x;  wxr[4*i+1]=a.y;  wxr[4*i+2]=a.z;  wxr[4*i+3]=a.w;
    wxz[4*i+0]=b4.x; wxz[4*i+1]=b4.y; wxz[4*i+2]=b4.z; wxz[4*i+3]=b4.w;
    wxn[4*i+0]=c.x;  wxn[4*i+1]=c.y;  wxn[4*i+2]=c.z;  wxn[4*i+3]=c.w;
  }
  const float br  = bias[jg];
  const float bz  = bias[H_ + jg];
  const float bni = bias[2*H_ + jg];
  const float bnh = bias_n[jg];

  // staging geometry (constant per thread): samples b0+pbb and b0+pbb+8, chunk pcl
  const int pbb = tid >> 6;            // [0,8)
  const int pcl = tid & 63;            // logical 16B chunk within the 256-f row
  const int psl = swz_(pcl);           // swizzled LDS slot
  // read-side slots for this thread's 8 x-values (logical chunks 2ks, 2ks+1)
  const int s0 = swz_(2*ks);
  const int s1 = swz_(2*ks+1);

  float* const hb0 = h_buf;
  float* const hb1 = h_buf + (size_t)B_*H_;
  int dead = 0;

  // ---- prologue: stage x(t=0) into xbuf[0] ----
#pragma unroll
  for (int it=0; it<2; ++it){
    const int bb = pbb + 8*it;
    const float4 v = *(const float4*)&x[((size_t)(b0+bb)*T_ + 0)*IN_ + pcl*4];
    *(float4*)&xbuf[0][bb*IN_ + psl*4] = v;
  }
  __syncthreads();

  for (int t=0; t<T_; ++t){
    const float* hc  = (t & 1) ? hb1 : hb0;
    float*       hnx = (t & 1) ? hb0 : hb1;

    // issue next-step x loads early (consumed by ds_write after compute)
    const int tl = (t+1 < T_) ? (t+1) : t;
    const float4 pf0 = *(const float4*)&x[((size_t)(b0+pbb  )*T_ + tl)*IN_ + pcl*4];
    const float4 pf1 = *(const float4*)&x[((size_t)(b0+pbb+8)*T_ + tl)*IN_ + pcl*4];

    const float* xl = xbuf[t & 1];

#pragma unroll 2
    for (int bb=0; bb<SG; ++bb){
      const float* hrowp = hc + (size_t)(b0+bb)*H_ + kh;
      float accr=0.f, accz=0.f, accnh=0.f, accni=0.f;
      const float4 h0 = *(const float4*)(hrowp + 0);
      const float4 h1 = *(const float4*)(hrowp + 4);
      const float4 h2 = *(const float4*)(hrowp + 8);
      const float4 h3 = *(const float4*)(hrowp + 12);
      FMA4(accr, h0, wr, 0);  FMA4(accr, h1, wr, 4);
      FMA4(accr, h2, wr, 8);  FMA4(accr, h3, wr, 12);
      FMA4(accz, h0, wz, 0);  FMA4(accz, h1, wz, 4);
      FMA4(accz, h2, wz, 8);  FMA4(accz, h3, wz, 12);
      FMA4(accnh,h0, wn, 0);  FMA4(accnh,h1, wn, 4);
      FMA4(accnh,h2, wn, 8);  FMA4(accnh,h3, wn, 12);
      const float4 xa = *(const float4*)&xl[bb*IN_ + s0*4];
      const float4 xb = *(const float4*)&xl[bb*IN_ + s1*4];
      FMA4(accr, xa, wxr, 0); FMA4(accr, xb, wxr, 4);
      FMA4(accz, xa, wxz, 0); FMA4(accz, xb, wxz, 4);
      FMA4(accni,xa, wxn, 0); FMA4(accni,xb, wxn, 4);
      // reduce across the 32 ks-lanes (in-wave, width 32)
#pragma unroll
      for (int m=1;m<32;m<<=1){
        accr  += __shfl_xor(accr,  m, 32);
        accz  += __shfl_xor(accz,  m, 32);
        accnh += __shfl_xor(accnh, m, 32);
        accni += __shfl_xor(accni, m, 32);
      }
      const float h_old = hc[(size_t)(b0+bb)*H_ + jg];
      const float r = sig_(accr + br);
      const float z = sig_(accz + bz);
      const float n = tanh_(accni + bni + r*(accnh + bnh));
      const float hnew = (1.0f - z)*n + z*h_old;
      if (ks == 0) hnew_sh[bb][j_loc] = hnew;
    }

    // park prefetched x into the other LDS buffer (its readers finished at t-1)
    {
      float* xn = xbuf[(t+1) & 1];
      *(float4*)&xn[(pbb  )*IN_ + psl*4] = pf0;
      *(float4*)&xn[(pbb+8)*IN_ + psl*4] = pf1;
    }
    __syncthreads();
    // coalesced write of this wg's j-slice for all 16 samples
    if (tid < 256)
      hnx[(size_t)(b0 + (tid>>4))*H_ + w*JT + (tid & 15)] = hnew_sh[tid>>4][tid&15];
    __threadfence();
    __syncthreads();
    // per-group barrier: monotonic counter, no reset within a launch
    if (tid == 0 && !dead){
      __hip_atomic_fetch_add(&counters[g*64], 1, __ATOMIC_RELEASE, __HIP_MEMORY_SCOPE_AGENT);
      const int target = WPG*(t+1);
      long long guard = 0;
      while (__hip_atomic_load(&counters[g*64], __ATOMIC_ACQUIRE, __HIP_MEMORY_SCOPE_AGENT) < target){
        __builtin_amdgcn_s_sleep(2);
        if (++guard > (1LL<<18)) { dead = 1; break; }
      }
    }
    __syncthreads();
  }
}

__global__ void head_k(const float* __restrict__ h, const float* __restrict__ W_out,
                       const float* __restrict__ b_out, float* __restrict__ out)
{
  const int b = (int)threadIdx.x;
  if (b < B_){
    float acc = 0.f;
    for (int k=0;k<H_;k++) acc = fmaf(h[(size_t)b*H_ + k], W_out[k], acc);
    out[b] = sig_(acc + b_out[0]);
  }
}

extern "C" void kernel_launch(void* const* d_in, const int* in_sizes, int n_in,
                              void* d_out, int out_size, void* d_ws, size_t ws_size,
                              hipStream_t stream)
{
  const float* x    = (const float*)d_in[0];
  const float* Wih  = (const float*)d_in[1];
  const float* Whh  = (const float*)d_in[2];
  const float* bias = (const float*)d_in[3];
  const float* bn   = (const float*)d_in[4];
  const float* Wout = (const float*)d_in[5];
  const float* bout = (const float*)d_in[6];
  float* out   = (float*)d_out;
  float* h_buf = (float*)d_ws;                                        // 2*128*512 f32 = 512KB
  int* counters = (int*)((char*)d_ws + (size_t)2*B_*H_*sizeof(float));

  // zero h0 + barrier counters every launch (captured into the graph)
  hipMemsetAsync(d_ws, 0, (size_t)2*B_*H_*sizeof(float) + 4096, stream);

  void* args[7];
  args[0]=(void*)&x; args[1]=(void*)&Wih; args[2]=(void*)&Whh; args[3]=(void*)&bias;
  args[4]=(void*)&bn; args[5]=(void*)&h_buf; args[6]=(void*)&counters;
  hipError_t e = hipLaunchCooperativeKernel((const void*)rnn_persist,
                                            dim3(256), dim3(NT), args, 0, stream);
  if (e != hipSuccess){
    (void)hipGetLastError();
    rnn_persist<<<dim3(256), dim3(NT), 0, stream>>>(x, Wih, Whh, bias, bn, h_buf, counters);
  }
  // T_ is even -> final h is in hb0
  head_k<<<dim3(1), dim3(128), 0, stream>>>(h_buf, Wout, bout, out);
}